// Round 13
// baseline (1567.764 us; speedup 1.0000x reference)
//
#include <hip/hip_runtime.h>
#include <hip/hip_bf16.h>

typedef __hip_bfloat16 bf16;
typedef __attribute__((ext_vector_type(8))) short short8v;
typedef __attribute__((ext_vector_type(4))) float float4v;

#define N_NODES 10000
#define E_EDGES 160000

__device__ __forceinline__ float b2f(bf16 v){ return __bfloat162float(v); }
__device__ __forceinline__ bf16 f2b(float v){ return __float2bfloat16(v); }

union U8 { int4 v; bf16 h[8]; };
union U4 { int2 v; bf16 h[4]; };

// ---- dtype-flexible external accessors (flag: 1 = bf16, 0 = f32) ----------
__device__ __forceinline__ float ldx(const void* p, size_t i, bool isb){
    return isb ? b2f(((const bf16*)p)[i]) : ((const float*)p)[i];
}
__device__ __forceinline__ void ld8(const void* p, size_t i, bool isb, float* o){
    if (isb) {
        U8 u; u.v = *reinterpret_cast<const int4*>((const bf16*)p + i);
        #pragma unroll
        for (int j = 0; j < 8; j++) o[j] = b2f(u.h[j]);
    } else {
        const float4* q = reinterpret_cast<const float4*>((const float*)p + i);
        float4 a = q[0], b = q[1];
        o[0]=a.x; o[1]=a.y; o[2]=a.z; o[3]=a.w; o[4]=b.x; o[5]=b.y; o[6]=b.z; o[7]=b.w;
    }
}
__device__ __forceinline__ void stx(void* p, size_t i, bool isb, float v){
    if (isb) ((bf16*)p)[i] = f2b(v); else ((float*)p)[i] = v;
}

// async global->LDS, 16 B/lane (HW: LDS dest = wave-uniform base + lane*16)
typedef const __attribute__((address_space(1))) void* gas_p;
typedef __attribute__((address_space(3))) void* las_p;
__device__ __forceinline__ void gl16(const bf16* g, bf16* l){
    __builtin_amdgcn_global_load_lds((gas_p)g, (las_p)l, 16, 0, 0);
}

// 4x4 in-register transpose across 4 lanes (verified r9-r11):
// input: a[r] = M[r][t] (t = lane&3); output: a[u] = M[t][u]
__device__ __forceinline__ void quadT(float* a, int t){
    float x0 = (t & 1) ? a[0] : a[1];
    float y0 = __shfl_xor(x0, 1);
    if (t & 1) a[0] = y0; else a[1] = y0;
    float x1 = (t & 1) ? a[2] : a[3];
    float y1 = __shfl_xor(x1, 1);
    if (t & 1) a[2] = y1; else a[3] = y1;
    float x2 = (t & 2) ? a[0] : a[2];
    float y2 = __shfl_xor(x2, 2);
    if (t & 2) a[0] = y2; else a[2] = y2;
    float x3 = (t & 2) ? a[1] : a[3];
    float y3 = __shfl_xor(x3, 2);
    if (t & 2) a[1] = y3; else a[3] = y3;
}

// XCD-bijective swizzle of a linear workgroup id
__device__ __forceinline__ int xcd_swz(int wg, int nwg){
    const int q = nwg >> 3, r = nwg & 7;
    const int xcd = wg & 7, ix = wg >> 3;
    return (xcd < r ? xcd * (q + 1) : r * (q + 1) + (xcd - r) * q) + ix;
}

// ---------------------------------------------------------------------------
__global__ void detect_dtype(const unsigned short* __restrict__ xw, int* __restrict__ flag){
    const int lane = threadIdx.x;  // 64 threads
    int cnt = 0;
    for (int i = lane; i < 8192; i += 64) {
        const unsigned e = (xw[i] >> 7) & 0xFF;
        if (e == 0 || (e >= 100 && e <= 140)) cnt++;
    }
    #pragma unroll
    for (int off = 32; off >= 1; off >>= 1) cnt += __shfl_xor(cnt, off);
    if (lane == 0) *flag = (cnt >= 6554) ? 1 : 0;
}

__global__ __launch_bounds__(256) void cvt_bf16(
    const void* __restrict__ in, bf16* __restrict__ out, long n8, const int* __restrict__ dflag)
{
    const bool isb = (*dflag != 0);
    const long t = (long)blockIdx.x * 256 + threadIdx.x;
    if (t >= n8) return;
    float f[8]; ld8(in, (size_t)t * 8, isb, f);
    U8 u;
    #pragma unroll
    for (int j = 0; j < 8; j++) u.h[j] = f2b(f[j]);
    *reinterpret_cast<int4*>(&out[t * 8]) = u.v;
}

// pack W[K,Nmat] -> Wt[Nmat][K] bf16
__global__ __launch_bounds__(256) void pack_wT(
    const void* __restrict__ W, bf16* __restrict__ out,
    int K, int Nmat, const int* __restrict__ dflag)
{
    const bool isb = (*dflag != 0);
    const int idx = blockIdx.x * 256 + threadIdx.x;
    if (idx >= K * Nmat) return;
    const int k = idx / Nmat, n = idx - k * Nmat;
    out[(size_t)n * K + k] = f2b(ldx(W, idx, isb));
}

// ---------------------------------------------------------------------------
// MFMA GEMM v7 (verified r10/r11): BK=64 single-buffer + quadT epilogue.
// BM=BN=128, 4 waves 2x2.  Node path.
// MODE 0: node QKV (Bt0|1|2 segmented NC=768; bias on col<256)
// MODE 3: FFN1 relu(+bias)
// ---------------------------------------------------------------------------
template<int MODE>
__global__ __launch_bounds__(256) void mg(
    const bf16* __restrict__ A, int M, int K, int NC,
    const bf16* __restrict__ Bt0, const bf16* __restrict__ Bt1, const bf16* __restrict__ Bt2,
    const void* __restrict__ bias,
    bf16* __restrict__ C,
    const int* __restrict__ dflag)
{
    const bool isb = (*dflag != 0);
    __shared__ __align__(16) bf16 Al[128 * 64];
    __shared__ __align__(16) bf16 Bl[128 * 64];
    __shared__ float biasl[128];

    const int tid = threadIdx.x;
    const int lane = tid & 63, wave = tid >> 6;
    const int l15 = lane & 15, g = lane >> 4;
    const int t4 = l15 & 3, qd = l15 >> 2;
    const int wr = wave >> 1, wc = wave & 1;

    const int nwgx = gridDim.x;
    int wg = xcd_swz(blockIdx.y * nwgx + blockIdx.x, nwgx * gridDim.y);
    const int rb = (wg / nwgx) * 128, cb = (wg % nwgx) * 128;

    const bf16* Bsel; int cloc;
    if (MODE == 0) {
        const int seg = cb >> 8;
        Bsel = (seg == 0) ? Bt0 : ((seg == 1) ? Bt1 : Bt2);
        cloc = cb & 255;
    } else { Bsel = Bt0; cloc = cb; }

    if (tid < 128) {
        float bv = 0.f;
        const int gc = cb + tid;
        if (MODE == 0) { if (gc < 256) bv = ldx(bias, gc, isb); }
        else bv = ldx(bias, gc, isb);
        biasl[tid] = bv;
    }

    const int sp = lane & 7, sr8 = lane >> 3;
    int rls[4]; long arows[4];
    #pragma unroll
    for (int j = 0; j < 4; j++) {
        const int rl = wave * 32 + j * 8 + sr8;
        rls[j] = rl;
        const int gm = rb + rl;
        arows[j] = (gm < M) ? gm : (M - 1);
    }

    float4v acc[4][4];
    #pragma unroll
    for (int i = 0; i < 4; i++)
        #pragma unroll
        for (int j = 0; j < 4; j++)
            acc[i][j] = (float4v){0.f, 0.f, 0.f, 0.f};

    for (int k0 = 0; k0 < K; k0 += 64) {
        #pragma unroll
        for (int j = 0; j < 4; j++) {
            const int rl = rls[j];
            const int pp = sp ^ (rl & 7);
            gl16(A + arows[j] * K + k0 + pp * 8,                 Al + rl * 64 + sp * 8);
            gl16(Bsel + (size_t)(cloc + rl) * K + k0 + pp * 8,   Bl + rl * 64 + sp * 8);
        }
        __syncthreads();
        #pragma unroll
        for (int ks = 0; ks < 2; ks++) {
            short8v av[4], bv[4];
            #pragma unroll
            for (int mi = 0; mi < 4; mi++) {
                const int row = wr * 64 + mi * 16 + l15;
                const int cp = (ks * 4 + g) ^ (row & 7);
                av[mi] = *reinterpret_cast<const short8v*>(&Al[row * 64 + cp * 8]);
            }
            #pragma unroll
            for (int ni = 0; ni < 4; ni++) {
                const int row = wc * 64 + ni * 16 + l15;
                const int cp = (ks * 4 + g) ^ (row & 7);
                bv[ni] = *reinterpret_cast<const short8v*>(&Bl[row * 64 + cp * 8]);
            }
            #pragma unroll
            for (int mi = 0; mi < 4; mi++)
                #pragma unroll
                for (int ni = 0; ni < 4; ni++)
                    acc[mi][ni] = __builtin_amdgcn_mfma_f32_16x16x32_bf16(
                        av[mi], bv[ni], acc[mi][ni], 0, 0, 0);
        }
        __syncthreads();
    }

    #pragma unroll
    for (int mi = 0; mi < 4; mi++) {
        const int grow = rb + wr * 64 + mi * 16 + g * 4 + t4;
        const bool ok = (grow < M);
        #pragma unroll
        for (int ni = 0; ni < 4; ni++) {
            float a[4];
            #pragma unroll
            for (int r = 0; r < 4; r++) a[r] = acc[mi][ni][r];
            quadT(a, t4);
            if (!ok) continue;
            const int ct = wc * 64 + ni * 16 + qd * 4;
            const int gc = cb + ct;
            if (MODE == 0) {
                if (gc < 256) {
                    #pragma unroll
                    for (int u = 0; u < 4; u++) a[u] += biasl[ct + u];
                }
            }
            if (MODE == 3) {
                #pragma unroll
                for (int u = 0; u < 4; u++) a[u] = fmaxf(a[u] + biasl[ct + u], 0.f);
            }
            U4 o;
            #pragma unroll
            for (int u = 0; u < 4; u++) o.h[u] = f2b(a[u]);
            *reinterpret_cast<int2*>(&C[(size_t)grow * NC + gc]) = o.v;
        }
    }
}

// ---------------------------------------------------------------------------
// LN-fused GEMM (verified r11): 512 thr, 8 waves (2x4), BM=128, BN=NC=256.
// Node path.  MODE 8: C bf16.  MODE 9: outv dtype-flex.
// ---------------------------------------------------------------------------
template<int MODE>
__global__ __launch_bounds__(512) void mgln(
    const bf16* __restrict__ A, int M, int K,
    const bf16* __restrict__ Bt,
    const void* __restrict__ bias,
    const bf16* __restrict__ resid,
    const void* __restrict__ lng, const void* __restrict__ lnb,
    bf16* __restrict__ C, void* __restrict__ outv, long obase,
    const int* __restrict__ dflag)
{
    const bool isb = (*dflag != 0);
    __shared__ __align__(16) bf16 Al[128 * 64];   // 16KB (Ps overlay)
    __shared__ __align__(16) bf16 Bl[256 * 64];   // 32KB (Mr/Rsd overlay)
    __shared__ float biasl[256];
    __shared__ float lngl[256];
    __shared__ float lnbl[256];

    const int tid = threadIdx.x;
    const int lane = tid & 63, wave = tid >> 6;
    const int l15 = lane & 15, g = lane >> 4;
    const int t4 = l15 & 3, qd = l15 >> 2;
    const int wr = wave >> 2, wc = wave & 3;   // 2 x 4 wave grid

    const int wg = xcd_swz(blockIdx.y, gridDim.y);
    const int rb = wg * 128;

    if (tid < 256) {
        biasl[tid] = ldx(bias, tid, isb);
        lngl[tid]  = ldx(lng,  tid, isb);
        lnbl[tid]  = ldx(lnb,  tid, isb);
    }

    const int sp = lane & 7, sr8 = lane >> 3;
    int rlA[2]; long arA[2];
    #pragma unroll
    for (int j = 0; j < 2; j++) {
        const int rl = wave * 16 + j * 8 + sr8;
        rlA[j] = rl;
        const int gm = rb + rl;
        arA[j] = (gm < M) ? gm : (M - 1);
    }
    int rlB[4];
    #pragma unroll
    for (int j = 0; j < 4; j++) rlB[j] = wave * 32 + j * 8 + sr8;

    float4v acc[4][4];
    #pragma unroll
    for (int i = 0; i < 4; i++)
        #pragma unroll
        for (int j = 0; j < 4; j++)
            acc[i][j] = (float4v){0.f, 0.f, 0.f, 0.f};

    for (int k0 = 0; k0 < K; k0 += 64) {
        #pragma unroll
        for (int j = 0; j < 2; j++) {
            const int pp = sp ^ (rlA[j] & 7);
            gl16(A + arA[j] * K + k0 + pp * 8, Al + rlA[j] * 64 + sp * 8);
        }
        #pragma unroll
        for (int j = 0; j < 4; j++) {
            const int pp = sp ^ (rlB[j] & 7);
            gl16(Bt + (size_t)rlB[j] * K + k0 + pp * 8, Bl + rlB[j] * 64 + sp * 8);
        }
        __syncthreads();
        #pragma unroll
        for (int ks = 0; ks < 2; ks++) {
            short8v av[4], bv[4];
            #pragma unroll
            for (int mi = 0; mi < 4; mi++) {
                const int row = wr * 64 + mi * 16 + l15;
                const int cp = (ks * 4 + g) ^ (row & 7);
                av[mi] = *reinterpret_cast<const short8v*>(&Al[row * 64 + cp * 8]);
            }
            #pragma unroll
            for (int ni = 0; ni < 4; ni++) {
                const int row = wc * 64 + ni * 16 + l15;
                const int cp = (ks * 4 + g) ^ (row & 7);
                bv[ni] = *reinterpret_cast<const short8v*>(&Bl[row * 64 + cp * 8]);
            }
            #pragma unroll
            for (int mi = 0; mi < 4; mi++)
                #pragma unroll
                for (int ni = 0; ni < 4; ni++)
                    acc[mi][ni] = __builtin_amdgcn_mfma_f32_16x16x32_bf16(
                        av[mi], bv[ni], acc[mi][ni], 0, 0, 0);
        }
        __syncthreads();
    }

    float s1[4] = {0.f,0.f,0.f,0.f}, s2[4] = {0.f,0.f,0.f,0.f};
    #pragma unroll
    for (int mi = 0; mi < 4; mi++) {
        const int grow = rb + wr * 64 + mi * 16 + g * 4 + t4;
        const bool ok = (grow < M);
        #pragma unroll
        for (int ni = 0; ni < 4; ni++) {
            float a[4];
            #pragma unroll
            for (int r = 0; r < 4; r++) a[r] = acc[mi][ni][r];
            quadT(a, t4);
            const int ct = wc * 64 + ni * 16 + qd * 4;
            U4 rr; rr.v = make_int2(0, 0);
            if (ok) rr.v = *reinterpret_cast<const int2*>(&resid[(size_t)grow * 256 + ct]);
            #pragma unroll
            for (int u = 0; u < 4; u++) {
                a[u] += biasl[ct + u] + b2f(rr.h[u]);
                s1[mi] += a[u];
                s2[mi] += a[u] * a[u];
                acc[mi][ni][u] = a[u];
            }
        }
    }
    float* Ps1 = (float*)Al;          // [16][128]
    float* Ps2 = Ps1 + 2048;
    #pragma unroll
    for (int mi = 0; mi < 4; mi++) {
        const int rowl = wr * 64 + mi * 16 + g * 4 + t4;
        Ps1[(wc * 4 + qd) * 128 + rowl] = s1[mi];
        Ps2[(wc * 4 + qd) * 128 + rowl] = s2[mi];
    }
    __syncthreads();
    float* Mr  = (float*)Bl;
    float* Rsd = Mr + 128;
    if (tid < 128) {
        float a1 = 0.f, a2 = 0.f;
        #pragma unroll
        for (int k = 0; k < 16; k++) { a1 += Ps1[k * 128 + tid]; a2 += Ps2[k * 128 + tid]; }
        const float mn = a1 * (1.f / 256.f);
        const float var = a2 * (1.f / 256.f) - mn * mn;
        Mr[tid] = mn;
        Rsd[tid] = rsqrtf(fmaxf(var, 0.f) + 1e-5f);
    }
    __syncthreads();
    #pragma unroll
    for (int mi = 0; mi < 4; mi++) {
        const int rowl = wr * 64 + mi * 16 + g * 4 + t4;
        const int grow = rb + rowl;
        if (grow >= M) continue;
        const float mn = Mr[rowl], rd = Rsd[rowl];
        #pragma unroll
        for (int ni = 0; ni < 4; ni++) {
            const int ct = wc * 64 + ni * 16 + qd * 4;
            float o[4];
            #pragma unroll
            for (int u = 0; u < 4; u++)
                o[u] = (acc[mi][ni][u] - mn) * rd * lngl[ct + u] + lnbl[ct + u];
            if (MODE == 8) {
                U4 ob;
                #pragma unroll
                for (int u = 0; u < 4; u++) ob.h[u] = f2b(o[u]);
                *reinterpret_cast<int2*>(&C[(size_t)grow * 256 + ct]) = ob.v;
            } else {
                if (isb) {
                    U4 ob;
                    #pragma unroll
                    for (int u = 0; u < 4; u++) ob.h[u] = f2b(o[u]);
                    *reinterpret_cast<int2*>((bf16*)outv + obase + (size_t)grow * 256 + ct) = ob.v;
                } else {
                    float4 f4 = make_float4(o[0], o[1], o[2], o[3]);
                    *reinterpret_cast<float4*>((float*)outv + obase + (size_t)grow * 256 + ct) = f4;
                }
            }
        }
    }
}

// ---------------------------------------------------------------------------
// mg2: 256x256-tile 2-phase double-buffered MFMA GEMM.  512 thr / 8 waves
// (2x4), per-wave 128x64 output, BK=64, LDS = exactly 128KB (4 x 32KB).
// Bias/LN params read directly from global in epilogue (1KB, L1-resident).
// MODE 7: edge QKV (seg 0:QE +bias+xg[sidx]; 1:KVE.k; 2:KVE.v +xg[didx])
// MODE 3: FFN1 relu(+bias), NC=1024
// MODE 8: Wo+bias+resid -> LN -> C bf16
// MODE 9: FFN2+bias+resid -> LN -> outv dtype-flex (K=1024)
// ---------------------------------------------------------------------------
template<int MODE>
__global__ __launch_bounds__(512, 2) void mg2(
    const bf16* __restrict__ A, int M, int K, int NC,
    const bf16* __restrict__ Bt0, const bf16* __restrict__ Bt1, const bf16* __restrict__ Bt2,
    const void* __restrict__ bias,
    const bf16* __restrict__ resid,
    const bf16* __restrict__ xg,
    const int* __restrict__ sidx, const int* __restrict__ didx,
    bf16* __restrict__ C, bf16* __restrict__ C2,
    const void* __restrict__ lng, const void* __restrict__ lnb,
    void* __restrict__ outv, long obase,
    const int* __restrict__ dflag)
{
    constexpr bool LNM = (MODE == 8 || MODE == 9);
    const bool isb = (*dflag != 0);
    __shared__ __align__(16) bf16 A0l[256 * 64];   // 32KB (Ps overlay)
    __shared__ __align__(16) bf16 B0l[256 * 64];   // 32KB (Mr/Rsd overlay)
    __shared__ __align__(16) bf16 A1l[256 * 64];   // 32KB
    __shared__ __align__(16) bf16 B1l[256 * 64];   // 32KB

    const int tid = threadIdx.x;
    const int lane = tid & 63, wave = tid >> 6;
    const int l15 = lane & 15, g = lane >> 4;
    const int t4 = l15 & 3, qd = l15 >> 2;
    const int wr = wave >> 2, wc = wave & 3;    // 2x4 wave grid; wave tile 128x64

    const int nwgx = gridDim.x;
    int wg = xcd_swz(blockIdx.y * nwgx + blockIdx.x, nwgx * gridDim.y);
    const int rb = (wg / nwgx) * 256, cb = (wg % nwgx) * 256;
    const int seg = (MODE == 7) ? (cb >> 8) : 0;

    const bf16* Bsel;
    int cloc;
    if (MODE == 7) { Bsel = (seg == 0) ? Bt0 : ((seg == 1) ? Bt1 : Bt2); cloc = 0; }
    else           { Bsel = Bt0; cloc = cb; }

    const int sp = lane & 7, sr8 = lane >> 3;
    int rls[4]; long arows[4];
    #pragma unroll
    for (int j = 0; j < 4; j++) {
        const int rl = wave * 32 + j * 8 + sr8;
        rls[j] = rl;
        const int gm = rb + rl;
        arows[j] = (gm < M) ? gm : (M - 1);
    }

    float4v acc[8][4];
    #pragma unroll
    for (int i = 0; i < 8; i++)
        #pragma unroll
        for (int j = 0; j < 4; j++)
            acc[i][j] = (float4v){0.f, 0.f, 0.f, 0.f};

    auto STAGE = [&](bf16* lA, bf16* lB, int k0) {
        #pragma unroll
        for (int j = 0; j < 4; j++) {
            const int rl = rls[j];
            const int pp = sp ^ (rl & 7);
            gl16(A + arows[j] * K + k0 + pp * 8,                 lA + rl * 64 + sp * 8);
            gl16(Bsel + (size_t)(cloc + rl) * K + k0 + pp * 8,   lB + rl * 64 + sp * 8);
        }
    };
    auto COMPUTE = [&](const bf16* lA, const bf16* lB) {
        #pragma unroll
        for (int ks = 0; ks < 2; ks++) {
            short8v av[8], bv[4];
            #pragma unroll
            for (int mi = 0; mi < 8; mi++) {
                const int row = wr * 128 + mi * 16 + l15;
                const int cp = (ks * 4 + g) ^ (row & 7);
                av[mi] = *reinterpret_cast<const short8v*>(&lA[row * 64 + cp * 8]);
            }
            #pragma unroll
            for (int ni = 0; ni < 4; ni++) {
                const int row = wc * 64 + ni * 16 + l15;
                const int cp = (ks * 4 + g) ^ (row & 7);
                bv[ni] = *reinterpret_cast<const short8v*>(&lB[row * 64 + cp * 8]);
            }
            #pragma unroll
            for (int mi = 0; mi < 8; mi++)
                #pragma unroll
                for (int ni = 0; ni < 4; ni++)
                    acc[mi][ni] = __builtin_amdgcn_mfma_f32_16x16x32_bf16(
                        av[mi], bv[ni], acc[mi][ni], 0, 0, 0);
        }
    };

    const int nt = K >> 6;   // 4 or 16 (even)
    STAGE(A0l, B0l, 0);
    __syncthreads();
    for (int t = 0; t + 2 < nt; t += 2) {
        STAGE(A1l, B1l, (t + 1) * 64);
        COMPUTE(A0l, B0l);
        __syncthreads();
        STAGE(A0l, B0l, (t + 2) * 64);
        COMPUTE(A1l, B1l);
        __syncthreads();
    }
    STAGE(A1l, B1l, (nt - 1) * 64);
    COMPUTE(A0l, B0l);
    __syncthreads();
    COMPUTE(A1l, B1l);

    if constexpr (!LNM) {
        #pragma unroll
        for (int mi = 0; mi < 8; mi++) {
            const int grow = rb + wr * 128 + mi * 16 + g * 4 + t4;
            const bool ok = (grow < M);
            int s5 = 0, d5 = 0;
            if (MODE == 7 && ok) {
                if (seg == 0) s5 = sidx[grow];
                else if (seg == 2) d5 = didx[grow];
            }
            #pragma unroll
            for (int ni = 0; ni < 4; ni++) {
                float a[4];
                #pragma unroll
                for (int r = 0; r < 4; r++) a[r] = acc[mi][ni][r];
                quadT(a, t4);
                if (!ok) continue;
                const int ct = wc * 64 + ni * 16 + qd * 4;
                if (MODE == 3) {
                    #pragma unroll
                    for (int u = 0; u < 4; u++)
                        a[u] = fmaxf(a[u] + ldx(bias, cb + ct + u, isb), 0.f);
                    U4 o;
                    #pragma unroll
                    for (int u = 0; u < 4; u++) o.h[u] = f2b(a[u]);
                    *reinterpret_cast<int2*>(&C[(size_t)grow * NC + cb + ct]) = o.v;
                } else {   // MODE 7
                    if (seg == 0) {
                        U4 xx; xx.v = *reinterpret_cast<const int2*>(&xg[(size_t)s5 * 256 + ct]);
                        #pragma unroll
                        for (int u = 0; u < 4; u++)
                            a[u] += ldx(bias, ct + u, isb) + b2f(xx.h[u]);
                        U4 o;
                        #pragma unroll
                        for (int u = 0; u < 4; u++) o.h[u] = f2b(a[u]);
                        *reinterpret_cast<int2*>(&C[(size_t)grow * 256 + ct]) = o.v;
                    } else if (seg == 1) {
                        U4 o;
                        #pragma unroll
                        for (int u = 0; u < 4; u++) o.h[u] = f2b(a[u]);
                        *reinterpret_cast<int2*>(&C2[(size_t)grow * 512 + ct]) = o.v;
                    } else {
                        U4 xx; xx.v = *reinterpret_cast<const int2*>(&xg[(size_t)d5 * 256 + ct]);
                        #pragma unroll
                        for (int u = 0; u < 4; u++) a[u] += b2f(xx.h[u]);
                        U4 o;
                        #pragma unroll
                        for (int u = 0; u < 4; u++) o.h[u] = f2b(a[u]);
                        *reinterpret_cast<int2*>(&C2[(size_t)grow * 512 + 256 + ct]) = o.v;
                    }
                }
            }
        }
    } else {
        // ===== LN-fused epilogue: block covers 256 rows x full 256 cols ====
        float s1[8] = {0,0,0,0,0,0,0,0}, s2[8] = {0,0,0,0,0,0,0,0};
        #pragma unroll
        for (int mi = 0; mi < 8; mi++) {
            const int grow = rb + wr * 128 + mi * 16 + g * 4 + t4;
            const bool ok = (grow < M);
            #pragma unroll
            for (int ni = 0; ni < 4; ni++) {
                float a[4];
                #pragma unroll
                for (int r = 0; r < 4; r++) a[r] = acc[mi][ni][r];
                quadT(a, t4);
                const int ct = wc * 64 + ni * 16 + qd * 4;
                U4 rr; rr.v = make_int2(0, 0);
                if (ok) rr.v = *reinterpret_cast<const int2*>(&resid[(size_t)grow * 256 + ct]);
                #pragma unroll
                for (int u = 0; u < 4; u++) {
                    a[u] += ldx(bias, ct + u, isb) + b2f(rr.h[u]);
                    s1[mi] += a[u];
                    s2[mi] += a[u] * a[u];
                    acc[mi][ni][u] = a[u];
                }
            }
        }
        float* Ps1 = (float*)A0l;          // [16][256] = 16KB
        float* Ps2 = Ps1 + 4096;           // +16KB (fits 32KB A0l)
        #pragma unroll
        for (int mi = 0; mi < 8; mi++) {
            const int rowl = wr * 128 + mi * 16 + g * 4 + t4;
            Ps1[(wc * 4 + qd) * 256 + rowl] = s1[mi];
            Ps2[(wc * 4 + qd) * 256 + rowl] = s2[mi];
        }
        __syncthreads();
        float* Mr  = (float*)B0l;
        float* Rsd = Mr + 256;
        if (tid < 256) {
            float a1 = 0.f, a2 = 0.f;
            #pragma unroll
            for (int k = 0; k < 16; k++) { a1 += Ps1[k * 256 + tid]; a2 += Ps2[k * 256 + tid]; }
            const float mn = a1 * (1.f / 256.f);
            const float var = a2 * (1.f / 256.f) - mn * mn;
            Mr[tid] = mn;
            Rsd[tid] = rsqrtf(fmaxf(var, 0.f) + 1e-5f);
        }
        __syncthreads();
        #pragma unroll
        for (int mi = 0; mi < 8; mi++) {
            const int rowl = wr * 128 + mi * 16 + g * 4 + t4;
            const int grow = rb + rowl;
            if (grow >= M) continue;
            const float mn = Mr[rowl], rd = Rsd[rowl];
            #pragma unroll
            for (int ni = 0; ni < 4; ni++) {
                const int ct = wc * 64 + ni * 16 + qd * 4;
                float o[4];
                #pragma unroll
                for (int u = 0; u < 4; u++)
                    o[u] = (acc[mi][ni][u] - mn) * rd * ldx(lng, ct + u, isb) + ldx(lnb, ct + u, isb);
                if (MODE == 8) {
                    U4 ob;
                    #pragma unroll
                    for (int u = 0; u < 4; u++) ob.h[u] = f2b(o[u]);
                    *reinterpret_cast<int2*>(&C[(size_t)grow * 256 + ct]) = ob.v;
                } else {
                    if (isb) {
                        U4 ob;
                        #pragma unroll
                        for (int u = 0; u < 4; u++) ob.h[u] = f2b(o[u]);
                        *reinterpret_cast<int2*>((bf16*)outv + obase + (size_t)grow * 256 + ct) = ob.v;
                    } else {
                        float4 f4 = make_float4(o[0], o[1], o[2], o[3]);
                        *reinterpret_cast<float4*>((float*)outv + obase + (size_t)grow * 256 + ct) = f4;
                    }
                }
            }
        }
    }
}

// ---------------------------------------------------------------------------
// Node attention: node d's 16 in-edges are d+j*N.  (verified r3-r11)
// ---------------------------------------------------------------------------
__global__ __launch_bounds__(256) void attn_node(
    const bf16* __restrict__ QKV, const int* __restrict__ lsrc,
    const bf16* __restrict__ lgx16, bf16* __restrict__ O)
{
    const int d = blockIdx.x;
    const int tid = threadIdx.x;
    const float q = b2f(QKV[(size_t)d * 768 + tid]);
    float acc = 0.f, z = 0.f;
    for (int j = 0; j < 16; j++) {
        const int i = d + j * N_NODES;
        const int s = lsrc[i];
        const float e = b2f(lgx16[(size_t)i * 256 + tid]);
        float p = (b2f(QKV[(size_t)s * 768 + 256 + tid]) + e) * q;
        #pragma unroll
        for (int off = 16; off >= 1; off >>= 1) p += __shfl_xor(p, off);
        const float sc = expf(fminf(fmaxf(p * 0.17677669529663687f, -10.f), 10.f));
        const float vv = b2f(QKV[(size_t)s * 768 + 512 + tid]) + e;
        acc += vv * sc; z += sc;
    }
    O[(size_t)d * 256 + tid] = f2b(acc / z);
}

// ---------------------------------------------------------------------------
// Edge attention: dst e's 2 in-edges are {lg_src[e], lg_src[e+E]}.
// ---------------------------------------------------------------------------
__global__ __launch_bounds__(256) void attn_edge_f(
    const bf16* __restrict__ QE, const bf16* __restrict__ KVE,
    const int* __restrict__ lgsrc, bf16* __restrict__ O, int r0, int rows)
{
    const int b = blockIdx.x;
    if (b >= rows) return;
    const int dst = r0 + b;
    const int tid = threadIdx.x;
    const float q = b2f(QE[(size_t)dst * 256 + tid]);
    float acc = 0.f, z = 0.f;
    #pragma unroll
    for (int j = 0; j < 2; j++) {
        const int s = lgsrc[dst + j * E_EDGES];
        const size_t kr = (size_t)s * 512;
        float p = b2f(KVE[kr + tid]) * q;
        #pragma unroll
        for (int off = 16; off >= 1; off >>= 1) p += __shfl_xor(p, off);
        const float sc = expf(fminf(fmaxf(p * 0.17677669529663687f, -10.f), 10.f));
        acc += b2f(KVE[kr + 256 + tid]) * sc; z += sc;
    }
    O[(size_t)b * 256 + tid] = f2b(acc / z);
}

// ---------------------------------------------------------------------------
extern "C" void kernel_launch(void* const* d_in, const int* in_sizes, int n_in,
                              void* d_out, int out_size, void* d_ws, size_t ws_size,
                              hipStream_t stream)
{
    const void* x   = d_in[0];
    const void* lgx = d_in[1];
    const int* local_src = (const int*)d_in[3];
    const int* lg_src    = (const int*)d_in[5];
    const int* src_ids   = (const int*)d_in[7];
    const int* dst_ids   = (const int*)d_in[8];

    const void *nWq = d_in[9],  *nbq = d_in[10], *nWk = d_in[11], *nWv = d_in[12],
               *nWo = d_in[13], *nbo = d_in[14], *nln1g = d_in[15], *nln1b = d_in[16],
               *nW1 = d_in[17], *nb1 = d_in[18], *nW2 = d_in[19], *nb2 = d_in[20],
               *nln2g = d_in[21], *nln2b = d_in[22];
    const void *eWq = d_in[23], *ebq = d_in[24], *eWk = d_in[25], *eWv = d_in[26],
               *eWo = d_in[27], *ebo = d_in[28], *eln1g = d_in[29], *eln1b = d_in[30],
               *eW1 = d_in[31], *eb1 = d_in[32], *eW2 = d_in[33], *eb2 = d_in[34],
               *eln2g = d_in[35], *eln2b = d_in[36];

    const dim3 blk(256);
    const dim3 blk2(512);

    // ws: dflag 256B | Wt packs 3MB | x16 5.12MB | lgx16 81.92MB | KVE | QE |
    //     chunk arena (OE/HE/FE per CH rows).  ws measured ~696MB (r4/r5/r7).
    int* dflag = (int*)d_ws;
    detect_dtype<<<1, 64, 0, stream>>>((const unsigned short*)x, dflag);

    bf16* pk = (bf16*)((char*)d_ws + 256);
    bf16 *pnWq = pk,            *pnWk = pk + 65536,   *pnWv = pk + 131072,
         *pnWo = pk + 196608,   *pnW1 = pk + 262144,  *pnW2 = pk + 524288,
         *peWq = pk + 786432,   *peWk = pk + 851968,  *peWv = pk + 917504,
         *peWo = pk + 983040,   *peW1 = pk + 1048576, *peW2 = pk + 1310720;
    bf16* x16   = pk + 1572864;
    bf16* lgx16 = x16 + (size_t)N_NODES * 256;

    cvt_bf16<<<1250,  blk, 0, stream>>>(x,   x16,   (long)N_NODES * 32, dflag);
    cvt_bf16<<<20000, blk, 0, stream>>>(lgx, lgx16, (long)E_EDGES * 32, dflag);

    pack_wT<<<256,  blk, 0, stream>>>(nWq, pnWq, 256, 256,  dflag);
    pack_wT<<<256,  blk, 0, stream>>>(nWk, pnWk, 256, 256,  dflag);
    pack_wT<<<256,  blk, 0, stream>>>(nWv, pnWv, 256, 256,  dflag);
    pack_wT<<<256,  blk, 0, stream>>>(nWo, pnWo, 256, 256,  dflag);
    pack_wT<<<1024, blk, 0, stream>>>(nW1, pnW1, 256, 1024, dflag);
    pack_wT<<<1024, blk, 0, stream>>>(nW2, pnW2, 1024, 256, dflag);
    pack_wT<<<256,  blk, 0, stream>>>(eWq, peWq, 256, 256,  dflag);
    pack_wT<<<256,  blk, 0, stream>>>(eWk, peWk, 256, 256,  dflag);
    pack_wT<<<256,  blk, 0, stream>>>(eWv, peWv, 256, 256,  dflag);
    pack_wT<<<256,  blk, 0, stream>>>(eWo, peWo, 256, 256,  dflag);
    pack_wT<<<1024, blk, 0, stream>>>(eW1, peW1, 256, 1024, dflag);
    pack_wT<<<1024, blk, 0, stream>>>(eW2, peW2, 1024, 256, dflag);

    // ===== node path: temps in d_out's dead out_lgx region (verified r3-r11)
    bf16* QKVN = (bf16*)((char*)d_out + (size_t)N_NODES * 256 * 4);
    bf16* ON   = QKVN + (size_t)N_NODES * 768;
    bf16* HN   = ON   + (size_t)N_NODES * 256;
    bf16* FN   = HN   + (size_t)N_NODES * 256;

    const int gx = (N_NODES + 127) / 128;   // 79
    mg<0><<<dim3(6, gx), blk, 0, stream>>>(x16, N_NODES, 256, 768,
        pnWq, pnWk, pnWv, nbq, QKVN, dflag);
    attn_node<<<N_NODES, blk, 0, stream>>>(QKVN, local_src, lgx16, ON);
    mgln<8><<<dim3(1, gx), blk2, 0, stream>>>(ON, N_NODES, 256,
        pnWo, nbo, x16, nln1g, nln1b, HN, nullptr, 0, dflag);
    mg<3><<<dim3(8, gx), blk, 0, stream>>>(HN, N_NODES, 256, 1024,
        pnW1, nullptr, nullptr, nb1, FN, dflag);
    mgln<9><<<dim3(1, gx), blk2, 0, stream>>>(FN, N_NODES, 1024,
        pnW2, nb2, HN, nln2g, nln2b, nullptr, d_out, 0, dflag);

    // ===== edge path: full-E QKV, then chunked post-attention stages =====
    const size_t hdr = 256 + 3145728 + (size_t)5120000 + (size_t)81920000;  // 90.19MB
    bf16* KVE = (bf16*)((char*)d_ws + hdr);                    // E x 512 (163.84MB)
    bf16* QE  = KVE + (size_t)E_EDGES * 512;                   // E x 256 (81.92MB)
    char* arena = (char*)(QE + (size_t)E_EDGES * 256);

    const size_t used = hdr + (size_t)E_EDGES * 768 * 2;       // 335.95MB
    long CH = (long)(((ws_size > used ? ws_size - used : 0) / 3072) / 256 * 256);
    if (CH > E_EDGES) CH = E_EDGES;
    if (CH < 256) CH = 256;

    bf16* OE = (bf16*)arena;                                   // CH x 256
    bf16* HE = OE + (size_t)CH * 256;                          // CH x 256
    bf16* FE = HE + (size_t)CH * 256;                          // CH x 1024

    const int geb = E_EDGES / 256;  // 625
    mg2<7><<<dim3(3, geb), blk2, 0, stream>>>(lgx16, E_EDGES, 256, 768,
        peWq, peWk, peWv, ebq, nullptr, x16, src_ids, dst_ids,
        QE, KVE, nullptr, nullptr, nullptr, 0, dflag);

    for (long r0 = 0; r0 < E_EDGES; r0 += CH) {
        const int rows = (int)(((E_EDGES - r0) < CH) ? (E_EDGES - r0) : CH);
        const int gm = (rows + 255) / 256;

        attn_edge_f<<<rows, blk, 0, stream>>>(QE, KVE, lg_src, OE, (int)r0, rows);
        mg2<8><<<dim3(1, gm), blk2, 0, stream>>>(OE, rows, 256, 256,
            peWo, nullptr, nullptr, ebo, lgx16 + (size_t)r0 * 256, nullptr, nullptr, nullptr,
            HE, nullptr, eln1g, eln1b, nullptr, 0, dflag);
        mg2<3><<<dim3(4, gm), blk2, 0, stream>>>(HE, rows, 256, 1024,
            peW1, nullptr, nullptr, eb1, nullptr, nullptr, nullptr, nullptr,
            FE, nullptr, nullptr, nullptr, nullptr, 0, dflag);
        mg2<9><<<dim3(1, gm), blk2, 0, stream>>>(FE, rows, 1024, 256,
            peW2, nullptr, nullptr, eb2, HE, nullptr, nullptr, nullptr,
            nullptr, nullptr, eln2g, eln2b, d_out,
            (long)N_NODES * 256 + r0 * 256, dflag);
    }
}

// Round 14
// 1031.856 us; speedup vs baseline: 1.5194x; 1.5194x over previous
//
#include <hip/hip_runtime.h>
#include <hip/hip_bf16.h>

typedef __hip_bfloat16 bf16;
typedef __attribute__((ext_vector_type(8))) short short8v;
typedef __attribute__((ext_vector_type(4))) float float4v;

#define N_NODES 10000
#define E_EDGES 160000

__device__ __forceinline__ float b2f(bf16 v){ return __bfloat162float(v); }
__device__ __forceinline__ bf16 f2b(float v){ return __float2bfloat16(v); }

union U8 { int4 v; bf16 h[8]; };
union U4 { int2 v; bf16 h[4]; };

// ---- dtype-flexible external accessors (flag: 1 = bf16, 0 = f32) ----------
__device__ __forceinline__ float ldx(const void* p, size_t i, bool isb){
    return isb ? b2f(((const bf16*)p)[i]) : ((const float*)p)[i];
}
__device__ __forceinline__ void ld8(const void* p, size_t i, bool isb, float* o){
    if (isb) {
        U8 u; u.v = *reinterpret_cast<const int4*>((const bf16*)p + i);
        #pragma unroll
        for (int j = 0; j < 8; j++) o[j] = b2f(u.h[j]);
    } else {
        const float4* q = reinterpret_cast<const float4*>((const float*)p + i);
        float4 a = q[0], b = q[1];
        o[0]=a.x; o[1]=a.y; o[2]=a.z; o[3]=a.w; o[4]=b.x; o[5]=b.y; o[6]=b.z; o[7]=b.w;
    }
}
__device__ __forceinline__ void stx(void* p, size_t i, bool isb, float v){
    if (isb) ((bf16*)p)[i] = f2b(v); else ((float*)p)[i] = v;
}

// async global->LDS, 16 B/lane (HW: LDS dest = wave-uniform base + lane*16)
typedef const __attribute__((address_space(1))) void* gas_p;
typedef __attribute__((address_space(3))) void* las_p;
__device__ __forceinline__ void gl16(const bf16* g, bf16* l){
    __builtin_amdgcn_global_load_lds((gas_p)g, (las_p)l, 16, 0, 0);
}

// 4x4 in-register transpose across 4 lanes (verified r9-r11):
// input: a[r] = M[r][t] (t = lane&3); output: a[u] = M[t][u]
__device__ __forceinline__ void quadT(float* a, int t){
    float x0 = (t & 1) ? a[0] : a[1];
    float y0 = __shfl_xor(x0, 1);
    if (t & 1) a[0] = y0; else a[1] = y0;
    float x1 = (t & 1) ? a[2] : a[3];
    float y1 = __shfl_xor(x1, 1);
    if (t & 1) a[2] = y1; else a[3] = y1;
    float x2 = (t & 2) ? a[0] : a[2];
    float y2 = __shfl_xor(x2, 2);
    if (t & 2) a[0] = y2; else a[2] = y2;
    float x3 = (t & 2) ? a[1] : a[3];
    float y3 = __shfl_xor(x3, 2);
    if (t & 2) a[1] = y3; else a[3] = y3;
}

// XCD-bijective swizzle of a linear workgroup id
__device__ __forceinline__ int xcd_swz(int wg, int nwg){
    const int q = nwg >> 3, r = nwg & 7;
    const int xcd = wg & 7, ix = wg >> 3;
    return (xcd < r ? xcd * (q + 1) : r * (q + 1) + (xcd - r) * q) + ix;
}

// ---------------------------------------------------------------------------
__global__ void detect_dtype(const unsigned short* __restrict__ xw, int* __restrict__ flag){
    const int lane = threadIdx.x;  // 64 threads
    int cnt = 0;
    for (int i = lane; i < 8192; i += 64) {
        const unsigned e = (xw[i] >> 7) & 0xFF;
        if (e == 0 || (e >= 100 && e <= 140)) cnt++;
    }
    #pragma unroll
    for (int off = 32; off >= 1; off >>= 1) cnt += __shfl_xor(cnt, off);
    if (lane == 0) *flag = (cnt >= 6554) ? 1 : 0;
}

__global__ __launch_bounds__(256) void cvt_bf16(
    const void* __restrict__ in, bf16* __restrict__ out, long n8, const int* __restrict__ dflag)
{
    const bool isb = (*dflag != 0);
    const long t = (long)blockIdx.x * 256 + threadIdx.x;
    if (t >= n8) return;
    float f[8]; ld8(in, (size_t)t * 8, isb, f);
    U8 u;
    #pragma unroll
    for (int j = 0; j < 8; j++) u.h[j] = f2b(f[j]);
    *reinterpret_cast<int4*>(&out[t * 8]) = u.v;
}

// pack W[K,Nmat] -> Wt[Nmat][K] bf16
__global__ __launch_bounds__(256) void pack_wT(
    const void* __restrict__ W, bf16* __restrict__ out,
    int K, int Nmat, const int* __restrict__ dflag)
{
    const bool isb = (*dflag != 0);
    const int idx = blockIdx.x * 256 + threadIdx.x;
    if (idx >= K * Nmat) return;
    const int k = idx / Nmat, n = idx - k * Nmat;
    out[(size_t)n * K + k] = f2b(ldx(W, idx, isb));
}

// ---------------------------------------------------------------------------
// MFMA GEMM v7 (verified r10/r11): BK=64 single-buffer + quadT epilogue.
// BM=BN=128, 4 waves 2x2.
// MODE 0: node QKV (Bt0|1|2 segmented NC=768; bias on col<256)
// MODE 3: FFN1 relu(+bias), NC=1024
// MODE 7: edge QKV fused (seg0 -> C=QE +bias+xg[sidx]; seg1 -> C2=KVE.k;
//         seg2 -> C2=KVE.v +xg[didx])
// ---------------------------------------------------------------------------
template<int MODE>
__global__ __launch_bounds__(256) void mg(
    const bf16* __restrict__ A, int M, int K, int NC,
    const bf16* __restrict__ Bt0, const bf16* __restrict__ Bt1, const bf16* __restrict__ Bt2,
    const void* __restrict__ bias,
    const bf16* __restrict__ resid,
    const bf16* __restrict__ xg,
    const int* __restrict__ sidx, const int* __restrict__ didx,
    bf16* __restrict__ C, bf16* __restrict__ C2,
    const int* __restrict__ dflag)
{
    const bool isb = (*dflag != 0);
    __shared__ __align__(16) bf16 Al[128 * 64];
    __shared__ __align__(16) bf16 Bl[128 * 64];
    __shared__ float biasl[128];

    const int tid = threadIdx.x;
    const int lane = tid & 63, wave = tid >> 6;
    const int l15 = lane & 15, g = lane >> 4;
    const int t4 = l15 & 3, qd = l15 >> 2;
    const int wr = wave >> 1, wc = wave & 1;

    const int nwgx = gridDim.x;
    int wg = xcd_swz(blockIdx.y * nwgx + blockIdx.x, nwgx * gridDim.y);
    const int rb = (wg / nwgx) * 128, cb = (wg % nwgx) * 128;

    const bf16* Bsel; int cloc;
    if (MODE == 0 || MODE == 7) {
        const int seg = cb >> 8;
        Bsel = (seg == 0) ? Bt0 : ((seg == 1) ? Bt1 : Bt2);
        cloc = cb & 255;
    } else { Bsel = Bt0; cloc = cb; }

    if (tid < 128) {
        float bv = 0.f;
        const int gc = cb + tid;
        if (MODE == 0 || MODE == 7) { if (gc < 256) bv = ldx(bias, gc, isb); }
        else bv = ldx(bias, gc, isb);
        biasl[tid] = bv;
    }

    const int sp = lane & 7, sr8 = lane >> 3;
    int rls[4]; long arows[4];
    #pragma unroll
    for (int j = 0; j < 4; j++) {
        const int rl = wave * 32 + j * 8 + sr8;
        rls[j] = rl;
        const int gm = rb + rl;
        arows[j] = (gm < M) ? gm : (M - 1);
    }

    float4v acc[4][4];
    #pragma unroll
    for (int i = 0; i < 4; i++)
        #pragma unroll
        for (int j = 0; j < 4; j++)
            acc[i][j] = (float4v){0.f, 0.f, 0.f, 0.f};

    for (int k0 = 0; k0 < K; k0 += 64) {
        #pragma unroll
        for (int j = 0; j < 4; j++) {
            const int rl = rls[j];
            const int pp = sp ^ (rl & 7);
            gl16(A + arows[j] * K + k0 + pp * 8,                 Al + rl * 64 + sp * 8);
            gl16(Bsel + (size_t)(cloc + rl) * K + k0 + pp * 8,   Bl + rl * 64 + sp * 8);
        }
        __syncthreads();
        #pragma unroll
        for (int ks = 0; ks < 2; ks++) {
            short8v av[4], bv[4];
            #pragma unroll
            for (int mi = 0; mi < 4; mi++) {
                const int row = wr * 64 + mi * 16 + l15;
                const int cp = (ks * 4 + g) ^ (row & 7);
                av[mi] = *reinterpret_cast<const short8v*>(&Al[row * 64 + cp * 8]);
            }
            #pragma unroll
            for (int ni = 0; ni < 4; ni++) {
                const int row = wc * 64 + ni * 16 + l15;
                const int cp = (ks * 4 + g) ^ (row & 7);
                bv[ni] = *reinterpret_cast<const short8v*>(&Bl[row * 64 + cp * 8]);
            }
            #pragma unroll
            for (int mi = 0; mi < 4; mi++)
                #pragma unroll
                for (int ni = 0; ni < 4; ni++)
                    acc[mi][ni] = __builtin_amdgcn_mfma_f32_16x16x32_bf16(
                        av[mi], bv[ni], acc[mi][ni], 0, 0, 0);
        }
        __syncthreads();
    }

    #pragma unroll
    for (int mi = 0; mi < 4; mi++) {
        const int grow = rb + wr * 64 + mi * 16 + g * 4 + t4;
        const bool ok = (grow < M);
        int s5 = 0, d5 = 0;
        if (MODE == 7 && ok) {
            if (cb < 256) s5 = sidx[grow];
            else if (cb >= 512) d5 = didx[grow];
        }
        #pragma unroll
        for (int ni = 0; ni < 4; ni++) {
            float a[4];
            #pragma unroll
            for (int r = 0; r < 4; r++) a[r] = acc[mi][ni][r];
            quadT(a, t4);
            if (!ok) continue;
            const int ct = wc * 64 + ni * 16 + qd * 4;
            const int gc = cb + ct;
            if (MODE == 0) {
                if (gc < 256) {
                    #pragma unroll
                    for (int u = 0; u < 4; u++) a[u] += biasl[ct + u];
                }
            }
            if (MODE == 3) {
                #pragma unroll
                for (int u = 0; u < 4; u++) a[u] = fmaxf(a[u] + biasl[ct + u], 0.f);
            }
            if (MODE == 7) {
                if (gc < 256) {
                    U4 xx; xx.v = *reinterpret_cast<const int2*>(&xg[(size_t)s5 * 256 + gc]);
                    #pragma unroll
                    for (int u = 0; u < 4; u++) a[u] += biasl[ct + u] + b2f(xx.h[u]);
                } else if (gc >= 512) {
                    U4 xx; xx.v = *reinterpret_cast<const int2*>(&xg[(size_t)d5 * 256 + (gc - 512)]);
                    #pragma unroll
                    for (int u = 0; u < 4; u++) a[u] += b2f(xx.h[u]);
                }
            }
            U4 o;
            #pragma unroll
            for (int u = 0; u < 4; u++) o.h[u] = f2b(a[u]);
            if (MODE == 7) {
                if (gc < 256) *reinterpret_cast<int2*>(&C[(size_t)grow * 256 + gc]) = o.v;
                else          *reinterpret_cast<int2*>(&C2[(size_t)grow * 512 + (gc - 256)]) = o.v;
            } else {
                *reinterpret_cast<int2*>(&C[(size_t)grow * NC + gc]) = o.v;
            }
        }
    }
}

// ---------------------------------------------------------------------------
// LN-fused GEMM (verified r11): 512 thr, 8 waves (2x4), BM=128, BN=NC=256.
// MODE 8: C bf16.  MODE 9: outv dtype-flex at element obase.
// ---------------------------------------------------------------------------
template<int MODE>
__global__ __launch_bounds__(512) void mgln(
    const bf16* __restrict__ A, int M, int K,
    const bf16* __restrict__ Bt,
    const void* __restrict__ bias,
    const bf16* __restrict__ resid,
    const void* __restrict__ lng, const void* __restrict__ lnb,
    bf16* __restrict__ C, void* __restrict__ outv, long obase,
    const int* __restrict__ dflag)
{
    const bool isb = (*dflag != 0);
    __shared__ __align__(16) bf16 Al[128 * 64];   // 16KB (Ps overlay)
    __shared__ __align__(16) bf16 Bl[256 * 64];   // 32KB (Mr/Rsd overlay)
    __shared__ float biasl[256];
    __shared__ float lngl[256];
    __shared__ float lnbl[256];

    const int tid = threadIdx.x;
    const int lane = tid & 63, wave = tid >> 6;
    const int l15 = lane & 15, g = lane >> 4;
    const int t4 = l15 & 3, qd = l15 >> 2;
    const int wr = wave >> 2, wc = wave & 3;   // 2 x 4 wave grid

    const int wg = xcd_swz(blockIdx.y, gridDim.y);
    const int rb = wg * 128;

    if (tid < 256) {
        biasl[tid] = ldx(bias, tid, isb);
        lngl[tid]  = ldx(lng,  tid, isb);
        lnbl[tid]  = ldx(lnb,  tid, isb);
    }

    const int sp = lane & 7, sr8 = lane >> 3;
    int rlA[2]; long arA[2];
    #pragma unroll
    for (int j = 0; j < 2; j++) {
        const int rl = wave * 16 + j * 8 + sr8;
        rlA[j] = rl;
        const int gm = rb + rl;
        arA[j] = (gm < M) ? gm : (M - 1);
    }
    int rlB[4];
    #pragma unroll
    for (int j = 0; j < 4; j++) rlB[j] = wave * 32 + j * 8 + sr8;

    float4v acc[4][4];
    #pragma unroll
    for (int i = 0; i < 4; i++)
        #pragma unroll
        for (int j = 0; j < 4; j++)
            acc[i][j] = (float4v){0.f, 0.f, 0.f, 0.f};

    for (int k0 = 0; k0 < K; k0 += 64) {
        #pragma unroll
        for (int j = 0; j < 2; j++) {
            const int pp = sp ^ (rlA[j] & 7);
            gl16(A + arA[j] * K + k0 + pp * 8, Al + rlA[j] * 64 + sp * 8);
        }
        #pragma unroll
        for (int j = 0; j < 4; j++) {
            const int pp = sp ^ (rlB[j] & 7);
            gl16(Bt + (size_t)rlB[j] * K + k0 + pp * 8, Bl + rlB[j] * 64 + sp * 8);
        }
        __syncthreads();
        #pragma unroll
        for (int ks = 0; ks < 2; ks++) {
            short8v av[4], bv[4];
            #pragma unroll
            for (int mi = 0; mi < 4; mi++) {
                const int row = wr * 64 + mi * 16 + l15;
                const int cp = (ks * 4 + g) ^ (row & 7);
                av[mi] = *reinterpret_cast<const short8v*>(&Al[row * 64 + cp * 8]);
            }
            #pragma unroll
            for (int ni = 0; ni < 4; ni++) {
                const int row = wc * 64 + ni * 16 + l15;
                const int cp = (ks * 4 + g) ^ (row & 7);
                bv[ni] = *reinterpret_cast<const short8v*>(&Bl[row * 64 + cp * 8]);
            }
            #pragma unroll
            for (int mi = 0; mi < 4; mi++)
                #pragma unroll
                for (int ni = 0; ni < 4; ni++)
                    acc[mi][ni] = __builtin_amdgcn_mfma_f32_16x16x32_bf16(
                        av[mi], bv[ni], acc[mi][ni], 0, 0, 0);
        }
        __syncthreads();
    }

    float s1[4] = {0.f,0.f,0.f,0.f}, s2[4] = {0.f,0.f,0.f,0.f};
    #pragma unroll
    for (int mi = 0; mi < 4; mi++) {
        const int grow = rb + wr * 64 + mi * 16 + g * 4 + t4;
        const bool ok = (grow < M);
        #pragma unroll
        for (int ni = 0; ni < 4; ni++) {
            float a[4];
            #pragma unroll
            for (int r = 0; r < 4; r++) a[r] = acc[mi][ni][r];
            quadT(a, t4);
            const int ct = wc * 64 + ni * 16 + qd * 4;
            U4 rr; rr.v = make_int2(0, 0);
            if (ok) rr.v = *reinterpret_cast<const int2*>(&resid[(size_t)grow * 256 + ct]);
            #pragma unroll
            for (int u = 0; u < 4; u++) {
                a[u] += biasl[ct + u] + b2f(rr.h[u]);
                s1[mi] += a[u];
                s2[mi] += a[u] * a[u];
                acc[mi][ni][u] = a[u];
            }
        }
    }
    float* Ps1 = (float*)Al;          // [16][128]
    float* Ps2 = Ps1 + 2048;
    #pragma unroll
    for (int mi = 0; mi < 4; mi++) {
        const int rowl = wr * 64 + mi * 16 + g * 4 + t4;
        Ps1[(wc * 4 + qd) * 128 + rowl] = s1[mi];
        Ps2[(wc * 4 + qd) * 128 + rowl] = s2[mi];
    }
    __syncthreads();
    float* Mr  = (float*)Bl;
    float* Rsd = Mr + 128;
    if (tid < 128) {
        float a1 = 0.f, a2 = 0.f;
        #pragma unroll
        for (int k = 0; k < 16; k++) { a1 += Ps1[k * 128 + tid]; a2 += Ps2[k * 128 + tid]; }
        const float mn = a1 * (1.f / 256.f);
        const float var = a2 * (1.f / 256.f) - mn * mn;
        Mr[tid] = mn;
        Rsd[tid] = rsqrtf(fmaxf(var, 0.f) + 1e-5f);
    }
    __syncthreads();
    #pragma unroll
    for (int mi = 0; mi < 4; mi++) {
        const int rowl = wr * 64 + mi * 16 + g * 4 + t4;
        const int grow = rb + rowl;
        if (grow >= M) continue;
        const float mn = Mr[rowl], rd = Rsd[rowl];
        #pragma unroll
        for (int ni = 0; ni < 4; ni++) {
            const int ct = wc * 64 + ni * 16 + qd * 4;
            float o[4];
            #pragma unroll
            for (int u = 0; u < 4; u++)
                o[u] = (acc[mi][ni][u] - mn) * rd * lngl[ct + u] + lnbl[ct + u];
            if (MODE == 8) {
                U4 ob;
                #pragma unroll
                for (int u = 0; u < 4; u++) ob.h[u] = f2b(o[u]);
                *reinterpret_cast<int2*>(&C[(size_t)grow * 256 + ct]) = ob.v;
            } else {
                if (isb) {
                    U4 ob;
                    #pragma unroll
                    for (int u = 0; u < 4; u++) ob.h[u] = f2b(o[u]);
                    *reinterpret_cast<int2*>((bf16*)outv + obase + (size_t)grow * 256 + ct) = ob.v;
                } else {
                    float4 f4 = make_float4(o[0], o[1], o[2], o[3]);
                    *reinterpret_cast<float4*>((float*)outv + obase + (size_t)grow * 256 + ct) = f4;
                }
            }
        }
    }
}

// ---------------------------------------------------------------------------
// Node attention (vectorized r14): wave per node, lane owns 4 cols (int2
// loads).  Head = 32 cols = 8 lanes; reduce via shfl_xor(4,2,1).
// Same math as r3-r11 verified scalar version.
// ---------------------------------------------------------------------------
__global__ __launch_bounds__(256) void attn_node(
    const bf16* __restrict__ QKV, const int* __restrict__ lsrc,
    const bf16* __restrict__ lgx16, bf16* __restrict__ O)
{
    const int w = threadIdx.x >> 6, lane = threadIdx.x & 63;
    const int d = blockIdx.x * 4 + w;
    if (d >= N_NODES) return;
    const int c4 = lane * 4;
    U4 uq; uq.v = *reinterpret_cast<const int2*>(&QKV[(size_t)d * 768 + c4]);
    float q[4];
    #pragma unroll
    for (int u = 0; u < 4; u++) q[u] = b2f(uq.h[u]);
    float acc[4] = {0.f, 0.f, 0.f, 0.f};
    float z = 0.f;
    for (int j = 0; j < 16; j++) {
        const int i = d + j * N_NODES;
        const int s = lsrc[i];
        U4 ue; ue.v = *reinterpret_cast<const int2*>(&lgx16[(size_t)i * 256 + c4]);
        U4 uk; uk.v = *reinterpret_cast<const int2*>(&QKV[(size_t)s * 768 + 256 + c4]);
        U4 uv; uv.v = *reinterpret_cast<const int2*>(&QKV[(size_t)s * 768 + 512 + c4]);
        float e[4], p = 0.f;
        #pragma unroll
        for (int u = 0; u < 4; u++) {
            e[u] = b2f(ue.h[u]);
            p += (b2f(uk.h[u]) + e[u]) * q[u];
        }
        p += __shfl_xor(p, 4); p += __shfl_xor(p, 2); p += __shfl_xor(p, 1);
        const float sc = expf(fminf(fmaxf(p * 0.17677669529663687f, -10.f), 10.f));
        #pragma unroll
        for (int u = 0; u < 4; u++) acc[u] += (b2f(uv.h[u]) + e[u]) * sc;
        z += sc;
    }
    U4 o;
    const float iz = 1.f / z;
    #pragma unroll
    for (int u = 0; u < 4; u++) o.h[u] = f2b(acc[u] * iz);
    *reinterpret_cast<int2*>(&O[(size_t)d * 256 + c4]) = o.v;
}

// ---------------------------------------------------------------------------
// Edge attention (vectorized r14): wave per dst, lane owns 4 cols.
// dst e's 2 in-edges are {lg_src[e], lg_src[e+E]}; KVE [E,512]=k|v.
// ---------------------------------------------------------------------------
__global__ __launch_bounds__(256) void attn_edge_f(
    const bf16* __restrict__ QE, const bf16* __restrict__ KVE,
    const int* __restrict__ lgsrc, bf16* __restrict__ O, int r0, int rows)
{
    const int w = threadIdx.x >> 6, lane = threadIdx.x & 63;
    const int b = blockIdx.x * 4 + w;
    if (b >= rows) return;
    const int dst = r0 + b;
    const int c4 = lane * 4;
    U4 uq; uq.v = *reinterpret_cast<const int2*>(&QE[(size_t)dst * 256 + c4]);
    float q[4];
    #pragma unroll
    for (int u = 0; u < 4; u++) q[u] = b2f(uq.h[u]);
    float acc[4] = {0.f, 0.f, 0.f, 0.f};
    float z = 0.f;
    #pragma unroll
    for (int j = 0; j < 2; j++) {
        const int s = lgsrc[dst + j * E_EDGES];
        const size_t kr = (size_t)s * 512;
        U4 uk; uk.v = *reinterpret_cast<const int2*>(&KVE[kr + c4]);
        U4 uv; uv.v = *reinterpret_cast<const int2*>(&KVE[kr + 256 + c4]);
        float p = 0.f;
        #pragma unroll
        for (int u = 0; u < 4; u++) p += b2f(uk.h[u]) * q[u];
        p += __shfl_xor(p, 4); p += __shfl_xor(p, 2); p += __shfl_xor(p, 1);
        const float sc = expf(fminf(fmaxf(p * 0.17677669529663687f, -10.f), 10.f));
        #pragma unroll
        for (int u = 0; u < 4; u++) acc[u] += b2f(uv.h[u]) * sc;
        z += sc;
    }
    U4 o;
    const float iz = 1.f / z;
    #pragma unroll
    for (int u = 0; u < 4; u++) o.h[u] = f2b(acc[u] * iz);
    *reinterpret_cast<int2*>(&O[(size_t)b * 256 + c4]) = o.v;
}

// ---------------------------------------------------------------------------
extern "C" void kernel_launch(void* const* d_in, const int* in_sizes, int n_in,
                              void* d_out, int out_size, void* d_ws, size_t ws_size,
                              hipStream_t stream)
{
    const void* x   = d_in[0];
    const void* lgx = d_in[1];
    const int* local_src = (const int*)d_in[3];
    const int* lg_src    = (const int*)d_in[5];
    const int* src_ids   = (const int*)d_in[7];
    const int* dst_ids   = (const int*)d_in[8];

    const void *nWq = d_in[9],  *nbq = d_in[10], *nWk = d_in[11], *nWv = d_in[12],
               *nWo = d_in[13], *nbo = d_in[14], *nln1g = d_in[15], *nln1b = d_in[16],
               *nW1 = d_in[17], *nb1 = d_in[18], *nW2 = d_in[19], *nb2 = d_in[20],
               *nln2g = d_in[21], *nln2b = d_in[22];
    const void *eWq = d_in[23], *ebq = d_in[24], *eWk = d_in[25], *eWv = d_in[26],
               *eWo = d_in[27], *ebo = d_in[28], *eln1g = d_in[29], *eln1b = d_in[30],
               *eW1 = d_in[31], *eb1 = d_in[32], *eW2 = d_in[33], *eb2 = d_in[34],
               *eln2g = d_in[35], *eln2b = d_in[36];

    const dim3 blk(256);
    const dim3 blk2(512);

    // ws: dflag 256B | Wt packs 3MB | x16 5.12MB | lgx16 81.92MB | KVE | QE |
    //     chunk arena.  ws measured ~696MB (r4/r5/r7 WRITE_SIZE signatures).
    int* dflag = (int*)d_ws;
    detect_dtype<<<1, 64, 0, stream>>>((const unsigned short*)x, dflag);

    bf16* pk = (bf16*)((char*)d_ws + 256);
    bf16 *pnWq = pk,            *pnWk = pk + 65536,   *pnWv = pk + 131072,
         *pnWo = pk + 196608,   *pnW1 = pk + 262144,  *pnW2 = pk + 524288,
         *peWq = pk + 786432,   *peWk = pk + 851968,  *peWv = pk + 917504,
         *peWo = pk + 983040,   *peW1 = pk + 1048576, *peW2 = pk + 1310720;
    bf16* x16   = pk + 1572864;
    bf16* lgx16 = x16 + (size_t)N_NODES * 256;

    cvt_bf16<<<1250,  blk, 0, stream>>>(x,   x16,   (long)N_NODES * 32, dflag);
    cvt_bf16<<<20000, blk, 0, stream>>>(lgx, lgx16, (long)E_EDGES * 32, dflag);

    pack_wT<<<256,  blk, 0, stream>>>(nWq, pnWq, 256, 256,  dflag);
    pack_wT<<<256,  blk, 0, stream>>>(nWk, pnWk, 256, 256,  dflag);
    pack_wT<<<256,  blk, 0, stream>>>(nWv, pnWv, 256, 256,  dflag);
    pack_wT<<<256,  blk, 0, stream>>>(nWo, pnWo, 256, 256,  dflag);
    pack_wT<<<1024, blk, 0, stream>>>(nW1, pnW1, 256, 1024, dflag);
    pack_wT<<<1024, blk, 0, stream>>>(nW2, pnW2, 1024, 256, dflag);
    pack_wT<<<256,  blk, 0, stream>>>(eWq, peWq, 256, 256,  dflag);
    pack_wT<<<256,  blk, 0, stream>>>(eWk, peWk, 256, 256,  dflag);
    pack_wT<<<256,  blk, 0, stream>>>(eWv, peWv, 256, 256,  dflag);
    pack_wT<<<256,  blk, 0, stream>>>(eWo, peWo, 256, 256,  dflag);
    pack_wT<<<1024, blk, 0, stream>>>(eW1, peW1, 256, 1024, dflag);
    pack_wT<<<1024, blk, 0, stream>>>(eW2, peW2, 1024, 256, dflag);

    // ===== node path: temps in d_out's dead out_lgx region (verified r3-r11)
    bf16* QKVN = (bf16*)((char*)d_out + (size_t)N_NODES * 256 * 4);
    bf16* ON   = QKVN + (size_t)N_NODES * 768;
    bf16* HN   = ON   + (size_t)N_NODES * 256;
    bf16* FN   = HN   + (size_t)N_NODES * 256;

    const int gx = (N_NODES + 127) / 128;   // 79
    mg<0><<<dim3(6, gx), blk, 0, stream>>>(x16, N_NODES, 256, 768,
        pnWq, pnWk, pnWv, nbq, nullptr, nullptr, nullptr, nullptr,
        QKVN, nullptr, dflag);
    attn_node<<<(N_NODES + 3) / 4, blk, 0, stream>>>(QKVN, local_src, lgx16, ON);
    mgln<8><<<dim3(1, gx), blk2, 0, stream>>>(ON, N_NODES, 256,
        pnWo, nbo, x16, nln1g, nln1b, HN, nullptr, 0, dflag);
    mg<3><<<dim3(8, gx), blk, 0, stream>>>(HN, N_NODES, 256, 1024,
        pnW1, nullptr, nullptr, nb1, nullptr, nullptr, nullptr, nullptr,
        FN, nullptr, dflag);
    mgln<9><<<dim3(1, gx), blk2, 0, stream>>>(FN, N_NODES, 1024,
        pnW2, nb2, HN, nln2g, nln2b, nullptr, d_out, 0, dflag);

    // ===== edge path =====
    const size_t hdr = 256 + 3145728 + (size_t)5120000 + (size_t)81920000;  // 90.19MB
    bf16* KVE = (bf16*)((char*)d_ws + hdr);                    // E x 512
    bf16* QE  = KVE + (size_t)E_EDGES * 512;                   // E x 256
    char* arena = (char*)(QE + (size_t)E_EDGES * 256);

    const size_t used = hdr + (size_t)E_EDGES * 768 * 2;       // 335.95MB
    long CH = (long)(((ws_size > used ? ws_size - used : 0) / 3072) / 128 * 128);
    if (CH > E_EDGES) CH = E_EDGES;
    if (CH < 128) CH = 128;

    bf16* OE = (bf16*)arena;                                   // CH x 256
    bf16* HE = OE + (size_t)CH * 256;                          // CH x 256
    bf16* FE = HE + (size_t)CH * 256;                          // CH x 1024

    const int ge = (E_EDGES + 127) / 128;  // 1250
    mg<7><<<dim3(6, ge), blk, 0, stream>>>(lgx16, E_EDGES, 256, 768,
        peWq, peWk, peWv, ebq, nullptr, x16, src_ids, dst_ids,
        QE, KVE, dflag);

    for (long r0 = 0; r0 < E_EDGES; r0 += CH) {
        const int rows = (int)(((E_EDGES - r0) < CH) ? (E_EDGES - r0) : CH);
        const int gm = (rows + 127) / 128;

        attn_edge_f<<<(rows + 3) / 4, blk, 0, stream>>>(QE, KVE, lg_src, OE, (int)r0, rows);
        mgln<8><<<dim3(1, gm), blk2, 0, stream>>>(OE, rows, 256,
            peWo, ebo, lgx16 + (size_t)r0 * 256, eln1g, eln1b, HE, nullptr, 0, dflag);
        mg<3><<<dim3(8, gm), blk, 0, stream>>>(HE, rows, 256, 1024,
            peW1, nullptr, nullptr, eb1, nullptr, nullptr, nullptr, nullptr,
            FE, nullptr, dflag);
        mgln<9><<<dim3(1, gm), blk2, 0, stream>>>(FE, rows, 1024,
            peW2, eb2, HE, eln2g, eln2b, nullptr, d_out,
            (long)N_NODES * 256 + r0 * 256, dflag);
    }
}